// Round 5
// baseline (321.440 us; speedup 1.0000x reference)
//
#include <hip/hip_runtime.h>
#include <hip/hip_bf16.h>

// NonLocalBlock B=4,C=256,H=W=64 (N=4096) — round 5.
//  wcvt : weights fp32 -> bf16 once
//  qkv  : FUSED q+k+v in one block (x read once, transposed in LDS)
//  attn : 32-query blocks, grid 512 -> 2 blocks/CU (real barrier overlap);
//         2 producer waves (QK+exp, K via global_load_lds dbuf),
//         2 consumer waves (c-split PV, in-step V loads, no fake reg-dbuf)
//  proj : streaming bf16 MFMA + residual
// ws = QT(=ATT) | KT | V | Wbf = 25.7 MiB.

typedef __attribute__((ext_vector_type(4))) short s16x4;
typedef __attribute__((ext_vector_type(8))) short s16x8;
typedef __attribute__((ext_vector_type(16))) float f32x16;

#define MFMA32(a, b, c) __builtin_amdgcn_mfma_f32_32x32x16_bf16((a), (b), (c), 0, 0, 0)

constexpr int Cc = 256;
constexpr int Nn = 4096;

__device__ inline short f2bf(float f) {
    unsigned int u = __builtin_bit_cast(unsigned int, f);
    u = (u + 0x7fffu + ((u >> 16) & 1u)) >> 16;   // RNE
    return (short)u;
}

__device__ inline void gl_lds16(const short* g, short* l) {
    // async global->LDS, 16 B/lane; LDS dest = wave-uniform base + lane*16
    __builtin_amdgcn_global_load_lds((const unsigned int*)g, (unsigned int*)l, 16, 0, 0);
}

// 32x32x16 bf16 MFMA layouts (m74/m101-verified C/D; A/B symmetric k-map):
//   A[m=lane&31][k=(lane>>5)*8+j]   B[k=(lane>>5)*8+j][n=lane&31]
//   C/D: col=lane&31, row=(r&3)+8*(r>>2)+4*(lane>>5)

// ---------------------------------------------------------------- wcvt
__global__ __launch_bounds__(256, 4) void wcvt_kernel(
    const float* __restrict__ wq, const float* __restrict__ wk,
    const float* __restrict__ wv, const float* __restrict__ wp,
    short* __restrict__ W)
{
    const int m = blockIdx.y;
    const float* src = (m == 0) ? wq : (m == 1) ? wk : (m == 2) ? wv : wp;
    const int idx = (blockIdx.x * 256 + threadIdx.x) * 8;
    float4 a = *(const float4*)(src + idx);
    float4 b = *(const float4*)(src + idx + 4);
    s16x8 p = { f2bf(a.x), f2bf(a.y), f2bf(a.z), f2bf(a.w),
                f2bf(b.x), f2bf(b.y), f2bf(b.z), f2bf(b.w) };
    *(s16x8*)(W + m * 65536 + idx) = p;
}

// ---------------------------------------------------------------- qkv (fused)
// grid (64 n-tiles, 4 b), 256 thr. One x-transpose, then Q,K,V back-to-back.
__global__ __launch_bounds__(256, 2) void qkv_kernel(
    const float* __restrict__ x, const short* __restrict__ W,
    const float* __restrict__ bq, const float* __restrict__ bk,
    const float* __restrict__ bv,
    short* __restrict__ QT, short* __restrict__ KT, short* __restrict__ V)
{
    const int nt = blockIdx.x, b = blockIdx.y;
    const int n0 = nt * 64;
    const int t = threadIdx.x, lane = t & 63, wid = t >> 6, h = lane >> 5, l31 = lane & 31;

    __shared__ alignas(16) short xT[64][264];      // x^T tile [n][c] bf16

    const float* xb = x + (size_t)b * Cc * Nn;
    #pragma unroll
    for (int r = 0; r < 16; ++r) {                 // transpose+cvt 64n x 256c
        int g = r * 256 + t;
        int n = g & 63, cg = g >> 6;
        float f0 = xb[(size_t)(4*cg + 0) * Nn + n0 + n];
        float f1 = xb[(size_t)(4*cg + 1) * Nn + n0 + n];
        float f2 = xb[(size_t)(4*cg + 2) * Nn + n0 + n];
        float f3 = xb[(size_t)(4*cg + 3) * Nn + n0 + n];
        s16x4 p = { f2bf(f0), f2bf(f1), f2bf(f2), f2bf(f3) };
        *(s16x4*)&xT[n][4*cg] = p;
    }
    __syncthreads();

    // ---- Q then K: D[n][o] = sum_c xT[n][c] w[o][c]
    const int mw = wid & 1, nwb = (wid >> 1) * 4;
    #pragma unroll
    for (int mat = 0; mat < 2; ++mat) {
        const short* Wm = W + mat * 65536;
        const float* bias = (mat == 0) ? bq : bk;
        f32x16 acc[4];
        #pragma unroll
        for (int s = 0; s < 4; ++s)
            #pragma unroll
            for (int r = 0; r < 16; ++r) acc[s][r] = 0.f;
        #pragma unroll 4
        for (int kk = 0; kk < 16; ++kk) {
            s16x8 a = *(const s16x8*)&xT[mw*32 + l31][kk*16 + h*8];
            #pragma unroll
            for (int s = 0; s < 4; ++s) {
                s16x8 bb = *(const s16x8*)&Wm[(size_t)((nwb + s)*32 + l31) * Cc + kk*16 + h*8];
                acc[s] = MFMA32(a, bb, acc[s]);
            }
        }
        short* dst = ((mat == 0) ? QT : KT) + (size_t)b * Nn * Cc;
        #pragma unroll
        for (int s = 0; s < 4; ++s) {
            int o = (nwb + s)*32 + l31;
            float bia = bias[o];
            #pragma unroll
            for (int r = 0; r < 16; ++r) {
                int n = mw*32 + (r & 3) + 8*(r >> 2) + 4*h;
                dst[(size_t)(n0 + n) * Cc + o] = f2bf(acc[s][r] + bia);
            }
        }
    }

    // ---- V: D[o][n] = sum_c w[o][c] xT[n][c]
    {
        const short* Wm = W + 2 * 65536;
        f32x16 acc[4];
        #pragma unroll
        for (int s = 0; s < 4; ++s)
            #pragma unroll
            for (int r = 0; r < 16; ++r) acc[s][r] = 0.f;
        #pragma unroll 4
        for (int kk = 0; kk < 16; ++kk) {
            s16x8 a0 = *(const s16x8*)&Wm[(size_t)((wid*2 + 0)*32 + l31) * Cc + kk*16 + h*8];
            s16x8 a1 = *(const s16x8*)&Wm[(size_t)((wid*2 + 1)*32 + l31) * Cc + kk*16 + h*8];
            s16x8 b0 = *(const s16x8*)&xT[ 0 + l31][kk*16 + h*8];
            s16x8 b1 = *(const s16x8*)&xT[32 + l31][kk*16 + h*8];
            acc[0] = MFMA32(a0, b0, acc[0]);
            acc[1] = MFMA32(a0, b1, acc[1]);
            acc[2] = MFMA32(a1, b0, acc[2]);
            acc[3] = MFMA32(a1, b1, acc[3]);
        }
        short* dst = V + (size_t)b * Cc * Nn;
        #pragma unroll
        for (int sub = 0; sub < 4; ++sub) {
            int mc = sub >> 1, nc = sub & 1;
            int nloc = nc*32 + l31;
            #pragma unroll
            for (int r = 0; r < 16; ++r) {
                int o = (wid*2 + mc)*32 + (r & 3) + 8*(r >> 2) + 4*h;
                dst[(size_t)o * Nn + n0 + nloc] = f2bf(acc[sub][r] + bv[o]);
            }
        }
    }
}

// ---------------------------------------------------------------- attn
// 32 queries/block, grid 512 -> 2 blocks/CU.  4 waves: wid 0-1 produce
// (QK+exp -> P), wid 2-3 consume (c-split 128 each, PV).
// LDS: Ks dbuf 64K + Ps dbuf 9K + misc = ~75 KB.
__global__ __launch_bounds__(256, 2) void attn_kernel(
    const short* __restrict__ QTg, const short* __restrict__ KTg,
    const short* __restrict__ Vg, short* __restrict__ ATT)
{
    const int bid = blockIdx.x;
    const int b  = (bid & 7) >> 1;              // batch per XCD pair
    const int qt = ((bid >> 3) << 1) | (bid & 1);
    const int i0 = qt * 32;

    const int t = threadIdx.x, lane = t & 63, wid = t >> 6, h = lane >> 5, l31 = lane & 31;

    __shared__ alignas(16) short Ks[2][64][256]; // swizzled granules (r4-verified)
    __shared__ alignas(16) short Ps[2][32][72];
    __shared__ float lpart[2][32];
    __shared__ float linv[32];
    short* KsF = &Ks[0][0][0];

    const short* Qb = QTg + (size_t)b * Nn * Cc;
    const short* Kb = KTg + (size_t)b * Nn * Cc;
    const short* Vb = Vg  + (size_t)b * Cc * Nn;

    const float SC = 0.09016844005f;            // C^-0.5 * log2(e)
    f32x16 oacc[4];

    if (wid < 2) {
        // ---------------- producer: S^T[j][i] = K^T[j][:]·Q[:,i], exp, P
        const int mj = wid;
        s16x8 qf[16];
        {
            const short* qrow = Qb + (size_t)(i0 + l31) * Cc + h*8;
            #pragma unroll
            for (int kc = 0; kc < 16; ++kc) qf[kc] = *(const s16x8*)(qrow + kc*16);
        }
        float lacc = 0.f;
        const int rl = mj*32 + l31;

        for (int tt = 0; tt < 66; ++tt) {
            if (tt < 64) {                       // DMA K tile tt
                const int kb = tt & 1;
                #pragma unroll
                for (int it = 0; it < 16; ++it) {
                    int r = (wid*16 + it)*2 + h;
                    int g = l31 ^ (r & 31);
                    const short* gp = Kb + (size_t)(tt*64 + r) * Cc + g*8;
                    short* lp = KsF + kb*16384 + (wid*16 + it)*512;
                    gl_lds16(gp, lp);
                }
            }
            if (tt >= 1 && tt < 65) {
                const int jt = tt - 1, kb = jt & 1;
                const short* abase = KsF + kb*16384 + rl*256;
                f32x16 s0, s1;
                #pragma unroll
                for (int r = 0; r < 16; ++r) { s0[r] = 0.f; s1[r] = 0.f; }
                #pragma unroll
                for (int kc = 0; kc < 8; ++kc) {
                    s16x8 a0 = *(const s16x8*)(abase + (((kc*4 + 0 + h) ^ l31) << 3));
                    s16x8 a1 = *(const s16x8*)(abase + (((kc*4 + 2 + h) ^ l31) << 3));
                    s0 = MFMA32(a0, qf[2*kc + 0], s0);
                    s1 = MFMA32(a1, qf[2*kc + 1], s1);
                }
                float ps[16], lsum = 0.f;
                #pragma unroll
                for (int r = 0; r < 16; ++r) {
                    float e = exp2f((s0[r] + s1[r]) * SC);
                    ps[r] = e; lsum += e;
                }
                lsum += __shfl_xor(lsum, 32);
                lacc += lsum;
                #pragma unroll
                for (int g = 0; g < 4; ++g) {
                    s16x4 pk = { f2bf(ps[4*g+0]), f2bf(ps[4*g+1]),
                                 f2bf(ps[4*g+2]), f2bf(ps[4*g+3]) };
                    *(s16x4*)&Ps[kb][l31][mj*32 + g*8 + 4*h] = pk;
                }
            }
            __syncthreads();
        }
        if (h == 0) lpart[mj][l31] = lacc;
    } else {
        // ---------------- consumer: O^T[c][i] += V[c][j] P[i][j], c-split 128
        const int w2 = wid - 2;
        #pragma unroll
        for (int s = 0; s < 4; ++s)
            #pragma unroll
            for (int r = 0; r < 16; ++r) oacc[s][r] = 0.f;

        for (int tt = 0; tt < 66; ++tt) {
            if (tt >= 2) {
                const int jt = tt - 2, j0 = jt * 64, pb = jt & 1;
                s16x8 vf[16], p0[4];
                #pragma unroll
                for (int sub = 0; sub < 4; ++sub) {
                    const short* vrow = Vb + (size_t)(w2*128 + sub*32 + l31) * Nn + j0 + h*8;
                    #pragma unroll
                    for (int kj = 0; kj < 4; ++kj)
                        vf[sub*4 + kj] = *(const s16x8*)(vrow + kj*16);
                }
                #pragma unroll
                for (int kj = 0; kj < 4; ++kj)
                    p0[kj] = *(const s16x8*)&Ps[pb][l31][kj*16 + h*8];
                #pragma unroll
                for (int sub = 0; sub < 4; ++sub)
                    #pragma unroll
                    for (int kj = 0; kj < 4; ++kj)
                        oacc[sub] = MFMA32(vf[sub*4 + kj], p0[kj], oacc[sub]);
            }
            __syncthreads();
        }
    }

    // ---------------- epilogue
    __syncthreads();
    if (t < 32) linv[t] = 1.0f / (lpart[0][t] + lpart[1][t]);
    __syncthreads();
    short (*T)[264] = (short(*)[264])KsF;       // scratch over Ks
    if (wid >= 2) {
        const int w2 = wid - 2;
        float rl2 = linv[l31];
        #pragma unroll
        for (int sub = 0; sub < 4; ++sub) {
            #pragma unroll
            for (int r = 0; r < 16; ++r) {
                int c = w2*128 + sub*32 + (r & 3) + 8*(r >> 2) + 4*h;
                T[l31][c] = f2bf(oacc[sub][r] * rl2);
            }
        }
    }
    __syncthreads();
    short* Ab = ATT + (size_t)b * Nn * Cc;      // [n][c]
    #pragma unroll
    for (int r = 0; r < 4; ++r) {
        int i = r*8 + (t >> 5), c8 = (t & 31) * 8;
        *(s16x8*)&Ab[(size_t)(i0 + i) * Cc + c8] = *(const s16x8*)&T[i][c8];
    }
}

// ---------------------------------------------------------------- proj
__global__ __launch_bounds__(256, 4) void proj_kernel(
    const short* __restrict__ ATT, const short* __restrict__ W,
    const float* __restrict__ bp, const float* __restrict__ x,
    float* __restrict__ out)
{
    const int nt = blockIdx.x, b = blockIdx.y, oh = blockIdx.z;
    const int n0 = nt * 64;
    const int t = threadIdx.x, lane = t & 63, wid = t >> 6, h = lane >> 5, l31 = lane & 31;
    const short* A = ATT + (size_t)b * Nn * Cc;
    const short* Wp = W + 3 * 65536;

    f32x16 acc[2];
    #pragma unroll
    for (int s = 0; s < 2; ++s)
        #pragma unroll
        for (int r = 0; r < 16; ++r) acc[s][r] = 0.f;

    const int og = oh*128 + wid*32;
    #pragma unroll 4
    for (int kk = 0; kk < 16; ++kk) {
        s16x8 a  = *(const s16x8*)&Wp[(size_t)(og + l31) * Cc + kk*16 + h*8];
        s16x8 b0 = *(const s16x8*)&A[(size_t)(n0 +  0 + l31) * Cc + kk*16 + h*8];
        s16x8 b1 = *(const s16x8*)&A[(size_t)(n0 + 32 + l31) * Cc + kk*16 + h*8];
        acc[0] = MFMA32(a, b0, acc[0]);
        acc[1] = MFMA32(a, b1, acc[1]);
    }

    const float* xb = x + (size_t)b * Cc * Nn;
    float* ob = out + (size_t)b * Cc * Nn;
    #pragma unroll
    for (int nc = 0; nc < 2; ++nc) {
        int nloc = nc*32 + l31;
        #pragma unroll
        for (int r = 0; r < 16; ++r) {
            int o = og + (r & 3) + 8*(r >> 2) + 4*h;
            size_t idx = (size_t)o * Nn + n0 + nloc;
            ob[idx] = xb[idx] + acc[nc][r] + bp[o];
        }
    }
}

// ---------------------------------------------------------------- launch
extern "C" void kernel_launch(void* const* d_in, const int* in_sizes, int n_in,
                              void* d_out, int out_size, void* d_ws, size_t ws_size,
                              hipStream_t stream)
{
    const float* x  = (const float*)d_in[0];
    const float* wq = (const float*)d_in[1];
    const float* bq = (const float*)d_in[2];
    const float* wk = (const float*)d_in[3];
    const float* bk = (const float*)d_in[4];
    const float* wv = (const float*)d_in[5];
    const float* bv = (const float*)d_in[6];
    const float* wp = (const float*)d_in[7];
    const float* bp = (const float*)d_in[8];

    const size_t elems = (size_t)4 * Nn * Cc;                 // 4.19 M / buffer
    const size_t need  = (3 * elems + 4 * 65536) * sizeof(short);  // 25.7 MiB
    if (ws_size < need) return;
    short* QT  = (short*)d_ws;                 // [b][n][c] bf16  (= ATT out)
    short* KT  = QT + elems;                   // [b][n][c] bf16
    short* V   = KT + elems;                   // [b][c][n] bf16
    short* Wbf = V + elems;                    // 4 x [o][c] bf16
    short* ATT = QT;                           // block-local self-overwrite
    (void)in_sizes; (void)n_in; (void)out_size;

    wcvt_kernel<<<dim3(32, 4), 256, 0, stream>>>(wq, wk, wv, wp, Wbf);
    qkv_kernel<<<dim3(64, 4), 256, 0, stream>>>(x, Wbf, bq, bk, bv, QT, KT, V);
    attn_kernel<<<dim3(512), 256, 0, stream>>>(QT, KT, V, ATT);
    proj_kernel<<<dim3(64, 4, 2), 256, 0, stream>>>(ATT, Wbf, bp, x, (float*)d_out);
}